// Round 8
// baseline (31.397 us; speedup 1.0000x reference)
//
#include <hip/hip_runtime.h>
#include <math.h>

#define T 16
#define A 8
#define H 128
#define E 32
#define G (4*H)   // 512 gate rows per LSTM

typedef _Float16 h2t __attribute__((ext_vector_type(2)));
typedef _Float16 h8t __attribute__((ext_vector_type(8)));

__device__ __forceinline__ float sigmoidf_(float x) {
    return 1.0f / (1.0f + __expf(-x));               // safe at both extremes
}
__device__ __forceinline__ float tanhf_(float x) {
    return 1.0f - 2.0f / (1.0f + __expf(2.0f * x));  // safe at both extremes
}

#if __has_builtin(__builtin_amdgcn_fdot2)
#define DOT2(a, b, c) __builtin_amdgcn_fdot2((a), (b), (c), false)
#else
__device__ __forceinline__ float dot2_fb(h2t a, h2t b, float c) {
    return fmaf((float)a[0], (float)b[0], fmaf((float)a[1], (float)b[1], c));
}
#define DOT2(a, b, c) dot2_fb((a), (b), (c))
#endif

#define RPT16(M) M(0) M(1) M(2) M(3) M(4) M(5) M(6) M(7) \
                 M(8) M(9) M(10) M(11) M(12) M(13) M(14) M(15)

// f16 weights in registers: 16 x h8t = 64 VGPRs. Total demand ~110 regs --
// under even the default 128-reg budget, so the allocator has no pressure
// reason to sink/spill (the f32 attempts at ~200 demand all failed).
__global__ __attribute__((amdgpu_flat_work_group_size(512, 512),
                          amdgpu_waves_per_eu(2, 2)))
void ppo_ctrl_kernel(const int* __restrict__ old_actions,
                     const float* __restrict__ init_input,
                     const float* __restrict__ W_ih_a, const float* __restrict__ W_hh_a,
                     const float* __restrict__ b_ih_a, const float* __restrict__ b_hh_a,
                     const float* __restrict__ heads_W, const float* __restrict__ heads_b,
                     const float* __restrict__ W_ih_c, const float* __restrict__ W_hh_c,
                     const float* __restrict__ b_ih_c, const float* __restrict__ b_hh_c,
                     const float* __restrict__ critic_W, const float* __restrict__ critic_b,
                     const float* __restrict__ embed,
                     float* __restrict__ out)
{
    const int tid  = threadIdx.x;
    const int lane = tid & 63;
    const int wv   = tid >> 6;          // 8 waves
    const bool actor = (blockIdx.x == 0);

    const float* W_ih = actor ? W_ih_a : W_ih_c;
    const float* W_hh = actor ? W_hh_a : W_hh_c;
    const float* b_ih = actor ? b_ih_a : b_ih_c;
    const float* b_hh = actor ? b_hh_a : b_hh_c;

    // LDS ~40.5 KB total (weight image gone)
    __shared__ __align__(16) float accx_s[T][G];     // 32 KB: bias + W_ih@x(t)
    __shared__ __align__(16) float gates_s[G];       // 2 KB
    __shared__ __align__(16) float x_s[T][E];        // 2 KB
    __shared__ __align__(16) _Float16 h16[H];        // 256 B
    __shared__ __align__(16) _Float16 hhist[T][H];   // 4 KB

    // ---- build x sequence (T*E == 512 == blockDim) ----
    {
        int t0 = tid >> 5, e0 = tid & 31;
        float v = (t0 == 0) ? init_input[e0]
                            : embed[((t0 - 1) * A + old_actions[t0 - 1]) * E + e0];
        x_s[t0][e0] = v;
    }

    // ---- W_hh row -> 16 pinned h8t registers (f32 load, cvt to f16) ----
    const float* rowp = W_hh + tid * H;
#define LOADW(i) h8t w##i; {                                              \
        float4 fa = *(const float4*)(rowp + 8*(i));                       \
        float4 fb = *(const float4*)(rowp + 8*(i) + 4);                   \
        w##i = (h8t){ (_Float16)fa.x, (_Float16)fa.y,                     \
                      (_Float16)fa.z, (_Float16)fa.w,                     \
                      (_Float16)fb.x, (_Float16)fb.y,                     \
                      (_Float16)fb.z, (_Float16)fb.w };                   \
        asm volatile("" : "+v"(w##i)); }
    RPT16(LOADW)
#undef LOADW

    // ---- W_ih row (transient) + bias ----
    const float* wir = W_ih + tid * E;
    float4 wi0 = *(const float4*)(wir +  0), wi1 = *(const float4*)(wir +  4),
           wi2 = *(const float4*)(wir +  8), wi3 = *(const float4*)(wir + 12),
           wi4 = *(const float4*)(wir + 16), wi5 = *(const float4*)(wir + 20),
           wi6 = *(const float4*)(wir + 24), wi7 = *(const float4*)(wir + 28);
    const float bias = b_ih[tid] + b_hh[tid];

    __syncthreads();   // x_s ready

    // ---- accx_s[t][row] = bias + W_ih[row]@x(t) (same-thread r/w later) ----
    #pragma unroll 1
    for (int t = 0; t < T; ++t) {
        float s0 = 0.f, s1 = 0.f, s2 = 0.f, s3 = 0.f;
#define MACI(i) { float4 xv = *(const float4*)(&x_s[t][4*(i)]);           \
        s0 = fmaf(wi##i.x, xv.x, s0); s1 = fmaf(wi##i.y, xv.y, s1);       \
        s2 = fmaf(wi##i.z, xv.z, s2); s3 = fmaf(wi##i.w, xv.w, s3); }
        MACI(0) MACI(1) MACI(2) MACI(3) MACI(4) MACI(5) MACI(6) MACI(7)
#undef MACI
        accx_s[t][tid] = bias + ((s0 + s1) + (s2 + s3));
    }

    float c_reg = 0.0f;                      // cell state (threads 0..127)
    const h8t* hv = (const h8t*)h16;         // 16 chunks; same-addr broadcast

    // ---- 16 sequential steps; weights stay in VGPRs, no LDS weight traffic ----
    #pragma unroll 1
    for (int t = 0; t < T; ++t) {
        float a0 = 0.f, a1 = 0.f, a2 = 0.f, a3 = 0.f;
        if (t != 0) {                        // t==0: h==0 -> dot is zero
#define MACC(i) { h8t hq = hv[i];                                          \
            a0 = DOT2(__builtin_shufflevector(w##i, w##i, 0, 1),           \
                      __builtin_shufflevector(hq,  hq,  0, 1), a0);        \
            a1 = DOT2(__builtin_shufflevector(w##i, w##i, 2, 3),           \
                      __builtin_shufflevector(hq,  hq,  2, 3), a1);        \
            a2 = DOT2(__builtin_shufflevector(w##i, w##i, 4, 5),           \
                      __builtin_shufflevector(hq,  hq,  4, 5), a2);        \
            a3 = DOT2(__builtin_shufflevector(w##i, w##i, 6, 7),           \
                      __builtin_shufflevector(hq,  hq,  6, 7), a3); }
            RPT16(MACC)
#undef MACC
        }
        gates_s[tid] = accx_s[t][tid] + ((a0 + a1) + (a2 + a3));
        __syncthreads();

        if (tid < H) {   // gate order i,f,g,o
            float gi = gates_s[tid],       gf = gates_s[tid + H];
            float gg = gates_s[tid + 2*H], go = gates_s[tid + 3*H];
            float cn = sigmoidf_(gf) * c_reg + sigmoidf_(gi) * tanhf_(gg);
            c_reg = cn;
            float hvv = sigmoidf_(go) * tanhf_(cn);
            _Float16 hf = (_Float16)hvv;
            h16[tid] = hf;
            hhist[t][tid] = hf;
        }
        __syncthreads();
    }

    // ---- heads: all 16 steps in parallel (off the serial path) ----
    if (actor) {
        #pragma unroll
        for (int rep = 0; rep < 2; ++rep) {
            const int tt = wv + rep * 8;           // wave wv -> t = wv, wv+8
            float hA = (float)hhist[tt][lane];
            float hB = (float)hhist[tt][64 + lane];
#define LOGIT(a) float l##a; {                                            \
            const float* hw = heads_W + (tt * A + (a)) * H;               \
            float p = fmaf(hw[lane], hA, hw[64 + lane] * hB);             \
            p += __shfl_xor(p, 1);  p += __shfl_xor(p, 2);                \
            p += __shfl_xor(p, 4);  p += __shfl_xor(p, 8);                \
            p += __shfl_xor(p, 16); p += __shfl_xor(p, 32);               \
            l##a = p + heads_b[tt * A + (a)]; }
            LOGIT(0) LOGIT(1) LOGIT(2) LOGIT(3)
            LOGIT(4) LOGIT(5) LOGIT(6) LOGIT(7)
#undef LOGIT
            if (lane == 0) {
                float m = fmaxf(fmaxf(fmaxf(l0, l1), fmaxf(l2, l3)),
                                fmaxf(fmaxf(l4, l5), fmaxf(l6, l7)));
                float e0 = __expf(l0 - m), e1 = __expf(l1 - m),
                      e2 = __expf(l2 - m), e3 = __expf(l3 - m),
                      e4 = __expf(l4 - m), e5 = __expf(l5 - m),
                      e6 = __expf(l6 - m), e7 = __expf(l7 - m);
                float s = ((e0 + e1) + (e2 + e3)) + ((e4 + e5) + (e6 + e7));
                float logZ = m + __logf(s);
                int act = old_actions[tt];
                float la = (act == 0) ? l0 : (act == 1) ? l1 : (act == 2) ? l2 :
                           (act == 3) ? l3 : (act == 4) ? l4 : (act == 5) ? l5 :
                           (act == 6) ? l6 : l7;
                out[tt] = la - logZ;                       // log_probs
                float w_ = e0*(l0-logZ) + e1*(l1-logZ) + e2*(l2-logZ) + e3*(l3-logZ)
                         + e4*(l4-logZ) + e5*(l5-logZ) + e6*(l6-logZ) + e7*(l7-logZ);
                out[T + tt] = -w_ / s;                     // entropies
            }
        }
    } else {
        #pragma unroll
        for (int rep = 0; rep < 2; ++rep) {
            const int tt = wv + rep * 8;
            float hA = (float)hhist[tt][lane];
            float hB = (float)hhist[tt][64 + lane];
            float p = fmaf(critic_W[lane], hA, critic_W[64 + lane] * hB);
            p += __shfl_xor(p, 1);  p += __shfl_xor(p, 2);
            p += __shfl_xor(p, 4);  p += __shfl_xor(p, 8);
            p += __shfl_xor(p, 16); p += __shfl_xor(p, 32);
            if (lane == 0) out[2 * T + tt] = p + critic_b[0];   // values
        }
    }
}

extern "C" void kernel_launch(void* const* d_in, const int* in_sizes, int n_in,
                              void* d_out, int out_size, void* d_ws, size_t ws_size,
                              hipStream_t stream) {
    const int*   old_actions = (const int*)  d_in[0];
    const float* init_input  = (const float*)d_in[1];
    const float* W_ih_a      = (const float*)d_in[2];
    const float* W_hh_a      = (const float*)d_in[3];
    const float* b_ih_a      = (const float*)d_in[4];
    const float* b_hh_a      = (const float*)d_in[5];
    const float* heads_W     = (const float*)d_in[6];
    const float* heads_b     = (const float*)d_in[7];
    const float* W_ih_c      = (const float*)d_in[8];
    const float* W_hh_c      = (const float*)d_in[9];
    const float* b_ih_c      = (const float*)d_in[10];
    const float* b_hh_c      = (const float*)d_in[11];
    const float* critic_W    = (const float*)d_in[12];
    const float* critic_b    = (const float*)d_in[13];
    const float* embed       = (const float*)d_in[14];
    float* out = (float*)d_out;

    ppo_ctrl_kernel<<<dim3(2), dim3(512), 0, stream>>>(
        old_actions, init_input,
        W_ih_a, W_hh_a, b_ih_a, b_hh_a,
        heads_W, heads_b,
        W_ih_c, W_hh_c, b_ih_c, b_hh_c,
        critic_W, critic_b, embed, out);
}

// Round 9
// 27.902 us; speedup vs baseline: 1.1253x; 1.1253x over previous
//
#include <hip/hip_runtime.h>
#include <math.h>

#define T 16
#define A 8
#define H 128
#define E 32
#define G (4*H)   // 512 gate rows per LSTM

// d_ws layout (bytes):
//   [0, 128K)          W_hh_a as f16, chunk-major: h8t at (c*512 + r)
//   [128K, 256K)       W_hh_c same
//   [256K, 272K)       accx_a f16 [t*512 + r]
//   [272K, 288K)       accx_c f16 [t*512 + r]
#define WS_WHH(L)   ((size_t)(L) * 131072u)
#define WS_ACCX(L)  (262144u + (size_t)(L) * 16384u)

typedef _Float16 h2t __attribute__((ext_vector_type(2)));
typedef _Float16 h8t __attribute__((ext_vector_type(8)));

__device__ __forceinline__ float sigmoidf_(float x) {
    return 1.0f / (1.0f + __expf(-x));               // safe at both extremes
}
__device__ __forceinline__ float tanhf_(float x) {
    return 1.0f - 2.0f / (1.0f + __expf(2.0f * x));  // safe at both extremes
}

#if __has_builtin(__builtin_amdgcn_fdot2)
#define DOT2(a, b, c) __builtin_amdgcn_fdot2((a), (b), (c), false)
#else
__device__ __forceinline__ float dot2_fb(h2t a, h2t b, float c) {
    return fmaf((float)a[0], (float)b[0], fmaf((float)a[1], (float)b[1], c));
}
#define DOT2(a, b, c) dot2_fb((a), (b), (c))
#endif

#define RPT16(M) M(0) M(1) M(2) M(3) M(4) M(5) M(6) M(7) \
                 M(8) M(9) M(10) M(11) M(12) M(13) M(14) M(15)

// ---------------- kernel 1: whole-GPU prologue (cold fetch + convert) -------
// blocks 0..63:   W_hh f32 -> f16 transpose-convert (one h8t chunk per thread)
// blocks 64..127: accx[t][r] = b_ih[r]+b_hh[r] + W_ih[r,:]@x(t)  (f16)
__global__ __launch_bounds__(256)
void ppo_prep_kernel(const int* __restrict__ old_actions,
                     const float* __restrict__ init_input,
                     const float* __restrict__ W_ih_a, const float* __restrict__ W_hh_a,
                     const float* __restrict__ b_ih_a, const float* __restrict__ b_hh_a,
                     const float* __restrict__ W_ih_c, const float* __restrict__ W_hh_c,
                     const float* __restrict__ b_ih_c, const float* __restrict__ b_hh_c,
                     const float* __restrict__ embed,
                     char* __restrict__ ws)
{
    const int b = blockIdx.x;
    if (b < 64) {
        // ---- convert: 16384 chunks total (2 LSTMs x 512 rows x 16 chunks) ----
        int tau  = b * 256 + threadIdx.x;       // [0, 16384)
        int lstm = tau >> 13;
        int i    = tau & 8191;
        int r    = i >> 4;                      // row 0..511
        int c    = i & 15;                      // chunk 0..15 (8 f32 each)
        const float* W = (lstm == 0) ? W_hh_a : W_hh_c;
        const float* src = W + r * H + c * 8;   // coalesced: c fast across lanes
        float4 fa = *(const float4*)(src);
        float4 fb = *(const float4*)(src + 4);
        h8t p = { (_Float16)fa.x, (_Float16)fa.y, (_Float16)fa.z, (_Float16)fa.w,
                  (_Float16)fb.x, (_Float16)fb.y, (_Float16)fb.z, (_Float16)fb.w };
        *(h8t*)(ws + WS_WHH(lstm) + (size_t)(c * 512 + r) * 16u) = p;
    } else {
        // ---- accx: 16384 dots (2 LSTMs x 16 steps x 512 rows) ----
        int tau  = (b - 64) * 256 + threadIdx.x;   // [0, 16384)
        int lstm = tau >> 13;
        int i    = tau & 8191;
        int t    = i >> 9;                      // step 0..15
        int r    = i & 511;                     // gate row 0..511
        const float* W_ih = (lstm == 0) ? W_ih_a : W_ih_c;
        const float* b_ih = (lstm == 0) ? b_ih_a : b_ih_c;
        const float* b_hh = (lstm == 0) ? b_hh_a : b_hh_c;
        const float* xp = (t == 0) ? init_input
                                   : embed + ((t - 1) * A + old_actions[t - 1]) * E;
        const float* wr = W_ih + r * E;
        float s0 = 0.f, s1 = 0.f, s2 = 0.f, s3 = 0.f;
        #pragma unroll
        for (int e = 0; e < E; e += 4) {
            float4 wv = *(const float4*)(wr + e);
            float4 xv = *(const float4*)(xp + e);
            s0 = fmaf(wv.x, xv.x, s0); s1 = fmaf(wv.y, xv.y, s1);
            s2 = fmaf(wv.z, xv.z, s2); s3 = fmaf(wv.w, xv.w, s3);
        }
        float acc = b_ih[r] + b_hh[r] + ((s0 + s1) + (s2 + s3));
        *(_Float16*)(ws + WS_ACCX(lstm) + (size_t)(t * 512 + r) * 2u) = (_Float16)acc;
    }
}

// ---------------- kernel 2: the serial recurrence (2 blocks) ----------------
__global__ __attribute__((amdgpu_flat_work_group_size(512, 512),
                          amdgpu_waves_per_eu(2, 2)))
void ppo_ctrl_kernel(const int* __restrict__ old_actions,
                     const float* __restrict__ heads_W, const float* __restrict__ heads_b,
                     const float* __restrict__ critic_W, const float* __restrict__ critic_b,
                     const char* __restrict__ ws,
                     float* __restrict__ out)
{
    const int tid  = threadIdx.x;
    const int lane = tid & 63;
    const int wv   = tid >> 6;          // 8 waves
    const int lstm = blockIdx.x;        // 0 = actor, 1 = critic
    const bool actor = (lstm == 0);

    __shared__ __align__(16) float gates_s[G];       // 2 KB
    __shared__ __align__(16) _Float16 h16[H];        // 256 B
    __shared__ __align__(16) _Float16 hhist[T][H];   // 4 KB

    // ---- stage W_hh row (f16) -> 16 pinned h8t regs; fully coalesced ----
    const char* wbase = ws + WS_WHH(lstm);
#define LOADW(i) h8t w##i = *(const h8t*)(wbase + (size_t)((i) * 512 + tid) * 16u); \
        asm volatile("" : "+v"(w##i));
    RPT16(LOADW)
#undef LOADW

    const _Float16* accg = (const _Float16*)(ws + WS_ACCX(lstm));

    float c_reg = 0.0f;                      // cell state (threads 0..127)
    const h8t* hv = (const h8t*)h16;         // broadcast reads: conflict-free

    // ---- 16 sequential steps; zero weight traffic in the loop ----
    #pragma unroll 1
    for (int t = 0; t < T; ++t) {
        float axv = (float)accg[t * 512 + tid];   // issued early, L2/L3-warm
        float a0 = 0.f, a1 = 0.f, a2 = 0.f, a3 = 0.f;
        if (t != 0) {                        // t==0: h==0 -> dot is zero
#define MACC(i) { h8t hq = hv[i];                                          \
            a0 = DOT2(__builtin_shufflevector(w##i, w##i, 0, 1),           \
                      __builtin_shufflevector(hq,  hq,  0, 1), a0);        \
            a1 = DOT2(__builtin_shufflevector(w##i, w##i, 2, 3),           \
                      __builtin_shufflevector(hq,  hq,  2, 3), a1);        \
            a2 = DOT2(__builtin_shufflevector(w##i, w##i, 4, 5),           \
                      __builtin_shufflevector(hq,  hq,  4, 5), a2);        \
            a3 = DOT2(__builtin_shufflevector(w##i, w##i, 6, 7),           \
                      __builtin_shufflevector(hq,  hq,  6, 7), a3); }
            RPT16(MACC)
#undef MACC
        }
        gates_s[tid] = axv + ((a0 + a1) + (a2 + a3));
        __syncthreads();

        if (tid < H) {   // gate order i,f,g,o
            float gi = gates_s[tid],       gf = gates_s[tid + H];
            float gg = gates_s[tid + 2*H], go = gates_s[tid + 3*H];
            float cn = sigmoidf_(gf) * c_reg + sigmoidf_(gi) * tanhf_(gg);
            c_reg = cn;
            float hvv = sigmoidf_(go) * tanhf_(cn);
            _Float16 hf = (_Float16)hvv;
            h16[tid] = hf;
            hhist[t][tid] = hf;
        }
        __syncthreads();
    }

    // ---- heads: all 16 steps in parallel (off the serial path) ----
    if (actor) {
        #pragma unroll
        for (int rep = 0; rep < 2; ++rep) {
            const int tt = wv + rep * 8;           // wave wv -> t = wv, wv+8
            float hA = (float)hhist[tt][lane];
            float hB = (float)hhist[tt][64 + lane];
#define LOGIT(a) float l##a; {                                            \
            const float* hw = heads_W + (tt * A + (a)) * H;               \
            float p = fmaf(hw[lane], hA, hw[64 + lane] * hB);             \
            p += __shfl_xor(p, 1);  p += __shfl_xor(p, 2);                \
            p += __shfl_xor(p, 4);  p += __shfl_xor(p, 8);                \
            p += __shfl_xor(p, 16); p += __shfl_xor(p, 32);               \
            l##a = p + heads_b[tt * A + (a)]; }
            LOGIT(0) LOGIT(1) LOGIT(2) LOGIT(3)
            LOGIT(4) LOGIT(5) LOGIT(6) LOGIT(7)
#undef LOGIT
            if (lane == 0) {
                float m = fmaxf(fmaxf(fmaxf(l0, l1), fmaxf(l2, l3)),
                                fmaxf(fmaxf(l4, l5), fmaxf(l6, l7)));
                float e0 = __expf(l0 - m), e1 = __expf(l1 - m),
                      e2 = __expf(l2 - m), e3 = __expf(l3 - m),
                      e4 = __expf(l4 - m), e5 = __expf(l5 - m),
                      e6 = __expf(l6 - m), e7 = __expf(l7 - m);
                float s = ((e0 + e1) + (e2 + e3)) + ((e4 + e5) + (e6 + e7));
                float logZ = m + __logf(s);
                int act = old_actions[tt];
                float la = (act == 0) ? l0 : (act == 1) ? l1 : (act == 2) ? l2 :
                           (act == 3) ? l3 : (act == 4) ? l4 : (act == 5) ? l5 :
                           (act == 6) ? l6 : l7;
                out[tt] = la - logZ;                       // log_probs
                float w_ = e0*(l0-logZ) + e1*(l1-logZ) + e2*(l2-logZ) + e3*(l3-logZ)
                         + e4*(l4-logZ) + e5*(l5-logZ) + e6*(l6-logZ) + e7*(l7-logZ);
                out[T + tt] = -w_ / s;                     // entropies
            }
        }
    } else {
        #pragma unroll
        for (int rep = 0; rep < 2; ++rep) {
            const int tt = wv + rep * 8;
            float hA = (float)hhist[tt][lane];
            float hB = (float)hhist[tt][64 + lane];
            float p = fmaf(critic_W[lane], hA, critic_W[64 + lane] * hB);
            p += __shfl_xor(p, 1);  p += __shfl_xor(p, 2);
            p += __shfl_xor(p, 4);  p += __shfl_xor(p, 8);
            p += __shfl_xor(p, 16); p += __shfl_xor(p, 32);
            if (lane == 0) out[2 * T + tt] = p + critic_b[0];   // values
        }
    }
}

extern "C" void kernel_launch(void* const* d_in, const int* in_sizes, int n_in,
                              void* d_out, int out_size, void* d_ws, size_t ws_size,
                              hipStream_t stream) {
    const int*   old_actions = (const int*)  d_in[0];
    const float* init_input  = (const float*)d_in[1];
    const float* W_ih_a      = (const float*)d_in[2];
    const float* W_hh_a      = (const float*)d_in[3];
    const float* b_ih_a      = (const float*)d_in[4];
    const float* b_hh_a      = (const float*)d_in[5];
    const float* heads_W     = (const float*)d_in[6];
    const float* heads_b     = (const float*)d_in[7];
    const float* W_ih_c      = (const float*)d_in[8];
    const float* W_hh_c      = (const float*)d_in[9];
    const float* b_ih_c      = (const float*)d_in[10];
    const float* b_hh_c      = (const float*)d_in[11];
    const float* critic_W    = (const float*)d_in[12];
    const float* critic_b    = (const float*)d_in[13];
    const float* embed       = (const float*)d_in[14];
    float* out = (float*)d_out;
    char* ws = (char*)d_ws;

    ppo_prep_kernel<<<dim3(128), dim3(256), 0, stream>>>(
        old_actions, init_input,
        W_ih_a, W_hh_a, b_ih_a, b_hh_a,
        W_ih_c, W_hh_c, b_ih_c, b_hh_c,
        embed, ws);

    ppo_ctrl_kernel<<<dim3(2), dim3(512), 0, stream>>>(
        old_actions, heads_W, heads_b, critic_W, critic_b, ws, out);
}